// Round 1
// baseline (769.919 us; speedup 1.0000x reference)
//
#include <hip/hip_runtime.h>
#include <hip/hip_bf16.h>

typedef __attribute__((ext_vector_type(4))) float f32x4;
typedef __attribute__((ext_vector_type(8))) short short8;

#define DEVI __device__ __forceinline__

DEVI unsigned short f2bf(float x) {
  union { float f; unsigned u; } v; v.f = x;
  unsigned r = v.u + 0x7fffu + ((v.u >> 16) & 1u);
  return (unsigned short)(r >> 16);
}
DEVI float bf2f(unsigned short h) {
  union { unsigned u; float f; } v; v.u = ((unsigned)h) << 16;
  return v.f;
}
DEVI short8 pack8(f32x4 lo, f32x4 hi) {
  short8 r;
  r[0] = (short)f2bf(lo[0]); r[1] = (short)f2bf(lo[1]);
  r[2] = (short)f2bf(lo[2]); r[3] = (short)f2bf(lo[3]);
  r[4] = (short)f2bf(hi[0]); r[5] = (short)f2bf(hi[1]);
  r[6] = (short)f2bf(hi[2]); r[7] = (short)f2bf(hi[3]);
  return r;
}

// ---------- prep: convert W_hh0 / W_hh1 to bf16 ----------
__global__ void prep_cvt(const float* __restrict__ a, const float* __restrict__ b,
                         short* __restrict__ oa, short* __restrict__ ob) {
  int i = blockIdx.x * 256 + threadIdx.x;
  if (i < 512 * 512) {
    oa[i] = (short)f2bf(a[i]);
    ob[i] = (short)f2bf(b[i]);
  }
}

// ---------- GEMM: pre = A @ W^T + bias_a + bias_b  (bf16 out) ----------
// A rows: GATHER -> embed[x[n,t]] (fp32, cvt on the fly);  else bf16 [65536][512]
// W: [512][KDIM] fp32 (row h contiguous in k -> already B^T form)
// out: [65536][512] bf16.  Tile 128x128, BK=64, 256 threads (2x2 waves of 64x64).
template<int KDIM, bool GATHER>
__global__ __launch_bounds__(256) void gemm_pre(
    const float* __restrict__ embed, const int* __restrict__ xtok,
    const short* __restrict__ Abf, const float* __restrict__ W,
    const float* __restrict__ bias_a, const float* __restrict__ bias_b,
    short* __restrict__ out) {
  __shared__ short smem[16384];          // As[128][64] @0, Bs[128][64] @8192 (shorts)
  short* As = smem;
  short* Bs = smem + 8192;

  const int tid = threadIdx.x;
  const int bM = (int)blockIdx.x >> 2;   // 512 M-tiles
  const int bN = (int)blockIdx.x & 3;    // 4 N-tiles
  const int m0 = bM * 128, n0 = bN * 128;

  f32x4 acc[4][4];
#pragma unroll
  for (int i = 0; i < 4; ++i)
#pragma unroll
    for (int j = 0; j < 4; ++j) acc[i][j] = (f32x4){0.f, 0.f, 0.f, 0.f};

  const int lane = tid & 63, wid = tid >> 6;
  const int wm = wid >> 1, wn = wid & 1;
  const int l15 = lane & 15, lk = lane >> 4;

  // staging: thread -> (row 0..127, k-half 0/32)
  const int srow = tid >> 1;
  const int skh = (tid & 1) * 32;
  const int sxor = (srow & 7) << 4;
  const int sbyte0 = srow * 128 + skh * 2;

  const float* aG = nullptr;
  const short* aB = nullptr;
  if (GATHER) {
    int r = m0 + srow;
    int t = r >> 11, n = r & 2047;
    int tok = xtok[(n << 5) + t];
    aG = embed + (size_t)tok * 256;
  } else {
    aB = Abf + (size_t)(m0 + srow) * 512;
  }
  const float* wRow = W + (size_t)(n0 + srow) * KDIM;

  for (int kb = 0; kb < KDIM; kb += 64) {
    __syncthreads();
    // stage A and B (fp32 -> bf16 cvt where needed), XOR-swizzled rows
#pragma unroll
    for (int c = 0; c < 4; ++c) {
      short8 pa;
      if (GATHER) {
        const float* src = aG + kb + skh + c * 8;
        f32x4 lo = *(const f32x4*)(src);
        f32x4 hi = *(const f32x4*)(src + 4);
        pa = pack8(lo, hi);
      } else {
        pa = *(const short8*)(aB + kb + skh + c * 8);
      }
      *(short8*)((char*)As + ((sbyte0 + c * 16) ^ sxor)) = pa;

      const float* bsrc = wRow + kb + skh + c * 8;
      f32x4 blo = *(const f32x4*)(bsrc);
      f32x4 bhi = *(const f32x4*)(bsrc + 4);
      *(short8*)((char*)Bs + ((sbyte0 + c * 16) ^ sxor)) = pack8(blo, bhi);
    }
    __syncthreads();
#pragma unroll
    for (int kt = 0; kt < 2; ++kt) {
      short8 av[4], bv[4];
#pragma unroll
      for (int mi = 0; mi < 4; ++mi) {
        int row = wm * 64 + mi * 16 + l15;
        int off = (row * 128 + kt * 64 + lk * 16) ^ ((row & 7) << 4);
        av[mi] = *(const short8*)((const char*)As + off);
      }
#pragma unroll
      for (int ni = 0; ni < 4; ++ni) {
        int col = wn * 64 + ni * 16 + l15;
        int off = (col * 128 + kt * 64 + lk * 16) ^ ((col & 7) << 4);
        bv[ni] = *(const short8*)((const char*)Bs + off);
      }
#pragma unroll
      for (int mi = 0; mi < 4; ++mi)
#pragma unroll
        for (int ni = 0; ni < 4; ++ni)
          acc[mi][ni] = __builtin_amdgcn_mfma_f32_16x16x32_bf16(av[mi], bv[ni], acc[mi][ni], 0, 0, 0);
    }
  }
  __syncthreads();
  // epilogue: bias add, bf16, stage through LDS (reuse smem as Cs[128][128] shorts)
  float bsum[4];
#pragma unroll
  for (int ni = 0; ni < 4; ++ni) {
    int cg = n0 + wn * 64 + ni * 16 + l15;
    bsum[ni] = bias_a[cg] + bias_b[cg];
  }
  short* Cs = smem;
#pragma unroll
  for (int mi = 0; mi < 4; ++mi)
#pragma unroll
    for (int ni = 0; ni < 4; ++ni)
#pragma unroll
      for (int r = 0; r < 4; ++r) {
        int row = wm * 64 + mi * 16 + lk * 4 + r;
        int col = wn * 64 + ni * 16 + l15;
        Cs[row * 128 + col] = (short)f2bf(acc[mi][ni][r] + bsum[ni]);
      }
  __syncthreads();
  {
    int row = tid >> 1, colh = (tid & 1) * 64;
    size_t gbase = (size_t)(m0 + row) * 512 + n0 + colh;
#pragma unroll
    for (int c = 0; c < 8; ++c)
      *(short8*)(out + gbase + c * 8) = *(const short8*)&Cs[row * 128 + colh + c * 8];
  }
}

// ---------- recurrence: h_t = relu(pre_t + h_{t-1} @ W_hh^T) ----------
// 128 blocks x 1024 threads (16 waves). Wave w owns output cols [32w,32w+32).
// W_hh slice register-stationary as MFMA B-fragments (loaded once).
template<bool WRITE_OUTS>
__global__ __launch_bounds__(1024) void recur(
    const short* __restrict__ pre,   // [32][2048][512] bf16
    const short* __restrict__ Wbf,   // [512][512] bf16
    short* __restrict__ outs,        // [32][2048][512] bf16 (WRITE_OUTS)
    float* __restrict__ hlast) {     // [2048][512] f32 (!WRITE_OUTS)
  __shared__ short hbuf[2][16 * 512];  // XOR-swizzled bf16, double buffered
  __shared__ short plds[16 * 512];     // linear bf16 pre tile
  const int tid = threadIdx.x;
  const int lane = tid & 63, wid = tid >> 6;
  const int l15 = lane & 15, lk = lane >> 4;
  const int n0 = (int)blockIdx.x * 16;

  // load W fragments once: wf[kt][f] covers k = kt*32 + lk*8 .. +8, col = wid*32+f*16+l15
  short8 wf[16][2];
#pragma unroll
  for (int kt = 0; kt < 16; ++kt)
#pragma unroll
    for (int f = 0; f < 2; ++f) {
      int col = wid * 32 + f * 16 + l15;
      wf[kt][f] = *(const short8*)(Wbf + (size_t)col * 512 + kt * 32 + lk * 8);
    }

  for (int i = tid; i < 16 * 512; i += 1024) hbuf[0][i] = 0;  // h_{-1} = 0

  const int axor = (l15 & 7) << 4;
  const int crow = tid >> 6;  // copy/staging row 0..15, lane covers 512 cols
  int cur = 0;
  for (int t = 0; t < 32; ++t) {
    __syncthreads();  // prev epilogue writes + plds reads done (or init done)
    if (WRITE_OUTS && t > 0) {
      int off = (crow * 1024 + lane * 16) ^ ((crow & 7) << 4);
      short8 v = *(const short8*)((const char*)hbuf[cur] + off);
      *(short8*)(outs + ((size_t)(t - 1) * 2048 + n0 + crow) * 512 + lane * 8) = v;
    }
    *(short8*)(plds + crow * 512 + lane * 8) =
        *(const short8*)(pre + ((size_t)t * 2048 + n0 + crow) * 512 + lane * 8);
    __syncthreads();  // plds ready
    f32x4 acc0 = {0.f, 0.f, 0.f, 0.f}, acc1 = {0.f, 0.f, 0.f, 0.f};
    const char* hb = (const char*)hbuf[cur];
#pragma unroll
    for (int kt = 0; kt < 16; ++kt) {
      int off = (l15 * 1024 + kt * 64 + lk * 16) ^ axor;
      short8 a = *(const short8*)(hb + off);
      acc0 = __builtin_amdgcn_mfma_f32_16x16x32_bf16(a, wf[kt][0], acc0, 0, 0, 0);
      acc1 = __builtin_amdgcn_mfma_f32_16x16x32_bf16(a, wf[kt][1], acc1, 0, 0, 0);
    }
    char* hn = (char*)hbuf[cur ^ 1];
#pragma unroll
    for (int f = 0; f < 2; ++f)
#pragma unroll
      for (int r = 0; r < 4; ++r) {
        int row = lk * 4 + r;
        int col = wid * 32 + f * 16 + l15;
        float v = (f ? acc1[r] : acc0[r]) + bf2f((unsigned short)plds[row * 512 + col]);
        v = fmaxf(v, 0.0f);
        *(short*)(hn + ((row * 1024 + col * 2) ^ ((row & 7) << 4))) = (short)f2bf(v);
        if (!WRITE_OUTS && t == 31) hlast[(size_t)(n0 + row) * 512 + col] = v;
      }
    cur ^= 1;
  }
  if (WRITE_OUTS) {
    __syncthreads();
    int off = (crow * 1024 + lane * 16) ^ ((crow & 7) << 4);
    short8 v = *(const short8*)((const char*)hbuf[cur] + off);
    *(short8*)(outs + ((size_t)31 * 2048 + n0 + crow) * 512 + lane * 8) = v;
  }
}

// ---------- head: s[b,n] = h_n.(wl-wg) + (sum_n h).wg + b_pred ----------
__global__ __launch_bounds__(512) void predict(
    const float* __restrict__ h1, const float* __restrict__ Wp,
    const float* __restrict__ bp, float* __restrict__ out) {
  const int b = blockIdx.x, tid = threadIdx.x;
  const int lane = tid & 63, wid = tid >> 6;
  __shared__ float red[8];
  __shared__ float sgd_s;
  const float* hb = h1 + (size_t)b * 256 * 512;
  float s = 0.f;
  for (int n = 0; n < 256; ++n) s += hb[(size_t)n * 512 + tid];
  float p = s * Wp[512 + tid];
#pragma unroll
  for (int o = 32; o; o >>= 1) p += __shfl_xor(p, o);
  if (lane == 0) red[wid] = p;
  __syncthreads();
  if (tid == 0) {
    float q = 0.f;
#pragma unroll
    for (int i = 0; i < 8; ++i) q += red[i];
    sgd_s = q;
  }
  __syncthreads();
  const float sgd = sgd_s + bp[0];
  float wd[8];
  const int k0 = lane * 8;
#pragma unroll
  for (int j = 0; j < 8; ++j) wd[j] = Wp[k0 + j] - Wp[512 + k0 + j];
  for (int c = 0; c < 32; ++c) {
    int n = wid * 32 + c;
    const float* hr = hb + (size_t)n * 512 + k0;
    float d = 0.f;
#pragma unroll
    for (int j = 0; j < 8; ++j) d += hr[j] * wd[j];
#pragma unroll
    for (int o = 1; o < 64; o <<= 1) d += __shfl_xor(d, o);
    if (lane == 0) out[b * 256 + n] = d + sgd;
  }
}

extern "C" void kernel_launch(void* const* d_in, const int* in_sizes, int n_in,
                              void* d_out, int out_size, void* d_ws, size_t ws_size,
                              hipStream_t stream) {
  const int* x = (const int*)d_in[0];
  const float* embed = (const float*)d_in[1];
  const float* Wih0 = (const float*)d_in[2];
  const float* Whh0 = (const float*)d_in[3];
  const float* bih0 = (const float*)d_in[4];
  const float* bhh0 = (const float*)d_in[5];
  const float* Wih1 = (const float*)d_in[6];
  const float* Whh1 = (const float*)d_in[7];
  const float* bih1 = (const float*)d_in[8];
  const float* bhh1 = (const float*)d_in[9];
  const float* Wpred = (const float*)d_in[10];
  const float* bpred = (const float*)d_in[11];
  float* out = (float*)d_out;

  char* ws = (char*)d_ws;
  short* whh0_bf = (short*)ws;                              // 512 KB
  short* whh1_bf = (short*)(ws + 524288);                   // 512 KB
  short* pre = (short*)(ws + 1048576);                      // 64 MB (pre0, then pre1)
  short* outs0 = (short*)(ws + 1048576 + 67108864);         // 64 MB
  float* h1 = (float*)(ws + 1048576 + 2ll * 67108864);      // 4 MB

  prep_cvt<<<1024, 256, 0, stream>>>(Whh0, Whh1, whh0_bf, whh1_bf);
  gemm_pre<256, true><<<2048, 256, 0, stream>>>(embed, x, nullptr, Wih0, bih0, bhh0, pre);
  recur<true><<<128, 1024, 0, stream>>>(pre, whh0_bf, outs0, nullptr);
  gemm_pre<512, false><<<2048, 256, 0, stream>>>(nullptr, nullptr, outs0, Wih1, bih1, bhh1, pre);
  recur<false><<<128, 1024, 0, stream>>>(pre, whh1_bf, nullptr, h1);
  predict<<<8, 512, 0, stream>>>(h1, Wpred, bpred, out);
}